// Round 1
// baseline (231.043 us; speedup 1.0000x reference)
//
#include <hip/hip_runtime.h>
#include <hip/hip_bf16.h>

#define B_   8
#define S_   1024
#define H_   768
#define NH_  12
#define DK_  64
#define M_   (B_ * S_)   // 8192

typedef __attribute__((ext_vector_type(8))) short          short8;
typedef __attribute__((ext_vector_type(8))) unsigned short ushort8;
typedef __attribute__((ext_vector_type(4))) float          f32x4;

__device__ __forceinline__ unsigned short f2bf(float x) {
    union { float f; unsigned u; } v; v.f = x;
    unsigned r = v.u + 0x7FFFu + ((v.u >> 16) & 1u);
    return (unsigned short)(r >> 16);
}

// ---------------------------------------------------------------------------
// y[M,N] = x[M,K] @ W[N,K]^T   (torch Linear, bias=False)
// 64x64 tile, BK=32, 4 waves (2x2 of 32x32), mfma_f32_16x16x32_bf16.
// fp32 (or bf16) input converted to bf16 during LDS staging.
// ---------------------------------------------------------------------------
template<bool IN_BF16, bool OUT_BF16>
__global__ __launch_bounds__(256)
void gemm_xwT(const void* __restrict__ Xv, const float* __restrict__ W,
              void* __restrict__ Yv, int M, int N, int K)
{
    __shared__ unsigned short As[64][40];   // 40 = 32 + 8 pad (80B rows, 16B aligned)
    __shared__ unsigned short Bs[64][40];

    const int tid  = threadIdx.x;
    const int bm   = blockIdx.x, bn = blockIdx.y;
    const int sr   = tid >> 2;            // staging row 0..63
    const int sc   = (tid & 3) * 8;       // staging col 0,8,16,24
    const int wid  = tid >> 6;
    const int lane = tid & 63;
    const int wr   = wid >> 1, wc = wid & 1;
    const int lg   = lane >> 4, lc = lane & 15;

    const float*          Xf = (const float*)Xv;
    const unsigned short* Xh = (const unsigned short*)Xv;

    f32x4 acc[2][2] = {};

    for (int k0 = 0; k0 < K; k0 += 32) {
        // --- stage A tile (64x32) ---
        {
            const size_t off = (size_t)(bm * 64 + sr) * K + k0 + sc;
            ushort8 a;
            if (IN_BF16) {
                a = *(const ushort8*)&Xh[off];
            } else {
                const float4 x0 = *(const float4*)&Xf[off];
                const float4 x1 = *(const float4*)&Xf[off + 4];
                a[0]=f2bf(x0.x); a[1]=f2bf(x0.y); a[2]=f2bf(x0.z); a[3]=f2bf(x0.w);
                a[4]=f2bf(x1.x); a[5]=f2bf(x1.y); a[6]=f2bf(x1.z); a[7]=f2bf(x1.w);
            }
            *(ushort8*)&As[sr][sc] = a;
        }
        // --- stage B tile (64x32) from W (always fp32) ---
        {
            const size_t off = (size_t)(bn * 64 + sr) * K + k0 + sc;
            const float4 x0 = *(const float4*)&W[off];
            const float4 x1 = *(const float4*)&W[off + 4];
            ushort8 bvv;
            bvv[0]=f2bf(x0.x); bvv[1]=f2bf(x0.y); bvv[2]=f2bf(x0.z); bvv[3]=f2bf(x0.w);
            bvv[4]=f2bf(x1.x); bvv[5]=f2bf(x1.y); bvv[6]=f2bf(x1.z); bvv[7]=f2bf(x1.w);
            *(ushort8*)&Bs[sr][sc] = bvv;
        }
        __syncthreads();

        short8 af[2], bfr[2];
#pragma unroll
        for (int mi = 0; mi < 2; mi++)
            af[mi] = *(const short8*)&As[wr * 32 + mi * 16 + lc][lg * 8];
#pragma unroll
        for (int ni = 0; ni < 2; ni++)
            bfr[ni] = *(const short8*)&Bs[wc * 32 + ni * 16 + lc][lg * 8];
#pragma unroll
        for (int mi = 0; mi < 2; mi++)
#pragma unroll
            for (int ni = 0; ni < 2; ni++)
                acc[mi][ni] = __builtin_amdgcn_mfma_f32_16x16x32_bf16(
                    af[mi], bfr[ni], acc[mi][ni], 0, 0, 0);
        __syncthreads();
    }

    // epilogue: C/D layout col = lane&15, row = (lane>>4)*4 + reg
#pragma unroll
    for (int mi = 0; mi < 2; mi++)
#pragma unroll
        for (int ni = 0; ni < 2; ni++)
#pragma unroll
            for (int reg = 0; reg < 4; reg++) {
                const int row = bm * 64 + wr * 32 + mi * 16 + lg * 4 + reg;
                const int col = bn * 64 + wc * 32 + ni * 16 + lc;
                const float val = acc[mi][ni][reg];
                if (OUT_BF16)
                    ((unsigned short*)Yv)[(size_t)row * N + col] = f2bf(val);
                else
                    ((float*)Yv)[(size_t)row * N + col] = val;
            }
}

// ---------------------------------------------------------------------------
// Flash attention: 1 block = (b, head, 64-row q tile). 4 waves x 16 q-rows.
// Online softmax wave-local (16-lane shfl reductions). V staged transposed.
// ---------------------------------------------------------------------------
__global__ __launch_bounds__(256)
void attn(const unsigned short* __restrict__ q,
          const unsigned short* __restrict__ k,
          const unsigned short* __restrict__ v,
          unsigned short* __restrict__ c)
{
    __shared__ unsigned short Qs[64][72];
    __shared__ unsigned short Ks[64][72];
    __shared__ unsigned short Vt[64][72];   // transposed: Vt[d][key]
    __shared__ unsigned short Ps[64][72];

    const int tid  = threadIdx.x;
    const int qt   = blockIdx.x, h = blockIdx.y, b = blockIdx.z;
    const int wid  = tid >> 6;
    const int lane = tid & 63;
    const int lg   = lane >> 4, lc = lane & 15;
    const size_t base = (size_t)b * S_ * H_ + (size_t)h * DK_;

    // stage Q tile (64 rows x 64 d)
    {
        const int r = tid >> 2, d0 = (tid & 3) * 16;
        const unsigned short* src = &q[base + (size_t)(qt * 64 + r) * H_ + d0];
        *(ushort8*)&Qs[r][d0]     = *(const ushort8*)src;
        *(ushort8*)&Qs[r][d0 + 8] = *(const ushort8*)(src + 8);
    }

    f32x4 o[4] = {};
    float mrow[4], lrow[4];
#pragma unroll
    for (int i = 0; i < 4; i++) { mrow[i] = -1e30f; lrow[i] = 0.f; }
    __syncthreads();

    for (int kt = 0; kt < S_ / 64; kt++) {
        // stage K tile + transposed V tile
        {
            const int r = tid >> 2, d0 = (tid & 3) * 16;
            const unsigned short* ksrc = &k[base + (size_t)(kt * 64 + r) * H_ + d0];
            *(ushort8*)&Ks[r][d0]     = *(const ushort8*)ksrc;
            *(ushort8*)&Ks[r][d0 + 8] = *(const ushort8*)(ksrc + 8);
            const unsigned short* vsrc = &v[base + (size_t)(kt * 64 + r) * H_ + d0];
            const ushort8 v0 = *(const ushort8*)vsrc;
            const ushort8 v1 = *(const ushort8*)(vsrc + 8);
#pragma unroll
            for (int j = 0; j < 8; j++) Vt[d0 + j][r]     = v0[j];
#pragma unroll
            for (int j = 0; j < 8; j++) Vt[d0 + 8 + j][r] = v1[j];
        }
        __syncthreads();

        // S = Q K^T  (wave's 16 rows x 64 keys)
        f32x4 s[4] = {};
        short8 aq[2];
#pragma unroll
        for (int ks = 0; ks < 2; ks++)
            aq[ks] = *(const short8*)&Qs[wid * 16 + lc][ks * 32 + lg * 8];
#pragma unroll
        for (int ni = 0; ni < 4; ni++)
#pragma unroll
            for (int ks = 0; ks < 2; ks++) {
                const short8 bk = *(const short8*)&Ks[ni * 16 + lc][ks * 32 + lg * 8];
                s[ni] = __builtin_amdgcn_mfma_f32_16x16x32_bf16(aq[ks], bk, s[ni], 0, 0, 0);
            }

        // online softmax (rows live at (lane>>4)*4+reg, cols at lane&15)
#pragma unroll
        for (int reg = 0; reg < 4; reg++) {
            float pmax = -1e30f;
#pragma unroll
            for (int ni = 0; ni < 4; ni++) {
                s[ni][reg] *= 0.125f;            // 1/sqrt(64)
                pmax = fmaxf(pmax, s[ni][reg]);
            }
#pragma unroll
            for (int d = 1; d < 16; d <<= 1)
                pmax = fmaxf(pmax, __shfl_xor(pmax, d, 64));
            const float mnew  = fmaxf(mrow[reg], pmax);
            const float scale = __expf(mrow[reg] - mnew);
            float psum = 0.f;
#pragma unroll
            for (int ni = 0; ni < 4; ni++) {
                const float p = __expf(s[ni][reg] - mnew);
                s[ni][reg] = p; psum += p;
            }
#pragma unroll
            for (int d = 1; d < 16; d <<= 1)
                psum += __shfl_xor(psum, d, 64);
            lrow[reg] = lrow[reg] * scale + psum;
            mrow[reg] = mnew;
            o[0][reg] *= scale; o[1][reg] *= scale;
            o[2][reg] *= scale; o[3][reg] *= scale;
        }

        // P -> LDS (per-wave region, wave-internal reuse; no barrier needed)
#pragma unroll
        for (int ni = 0; ni < 4; ni++)
#pragma unroll
            for (int reg = 0; reg < 4; reg++)
                Ps[wid * 16 + lg * 4 + reg][ni * 16 + lc] = f2bf(s[ni][reg]);

        short8 pa[2];
#pragma unroll
        for (int ks = 0; ks < 2; ks++)
            pa[ks] = *(const short8*)&Ps[wid * 16 + lc][ks * 32 + lg * 8];
#pragma unroll
        for (int ni = 0; ni < 4; ni++)
#pragma unroll
            for (int ks = 0; ks < 2; ks++) {
                const short8 bv = *(const short8*)&Vt[ni * 16 + lc][ks * 32 + lg * 8];
                o[ni] = __builtin_amdgcn_mfma_f32_16x16x32_bf16(pa[ks], bv, o[ni], 0, 0, 0);
            }
        __syncthreads();
    }

    // write context (bf16) to c[B,S,H]
#pragma unroll
    for (int ni = 0; ni < 4; ni++)
#pragma unroll
        for (int reg = 0; reg < 4; reg++) {
            const int row = qt * 64 + wid * 16 + lg * 4 + reg;
            const float val = o[ni][reg] / lrow[reg];
            c[base + (size_t)row * H_ + ni * 16 + lc] = f2bf(val);
        }
}

// ---------------------------------------------------------------------------
extern "C" void kernel_launch(void* const* d_in, const int* in_sizes, int n_in,
                              void* d_out, int out_size, void* d_ws, size_t ws_size,
                              hipStream_t stream)
{
    const float* Q  = (const float*)d_in[0];
    const float* K  = (const float*)d_in[1];
    const float* V  = (const float*)d_in[2];
    const float* Wq = (const float*)d_in[3];
    const float* Wk = (const float*)d_in[4];
    const float* Wv = (const float*)d_in[5];
    const float* Wo = (const float*)d_in[6];

    unsigned short* qb = (unsigned short*)d_ws;
    unsigned short* kb = qb + (size_t)M_ * H_;
    unsigned short* vb = kb + (size_t)M_ * H_;
    unsigned short* cb = vb + (size_t)M_ * H_;

    const dim3 gg(M_ / 64, H_ / 64);   // 128 x 12

    gemm_xwT<false, true><<<gg, 256, 0, stream>>>(Q, Wq, qb, M_, H_, H_);
    gemm_xwT<false, true><<<gg, 256, 0, stream>>>(K, Wk, kb, M_, H_, H_);
    gemm_xwT<false, true><<<gg, 256, 0, stream>>>(V, Wv, vb, M_, H_, H_);

    attn<<<dim3(S_ / 64, NH_, B_), 256, 0, stream>>>(qb, kb, vb, cb);

    gemm_xwT<true, false><<<gg, 256, 0, stream>>>(cb, Wo, (float*)d_out, M_, H_, H_);
}

// Round 2
// 212.049 us; speedup vs baseline: 1.0896x; 1.0896x over previous
//
#include <hip/hip_runtime.h>
#include <hip/hip_bf16.h>

#define B_   8
#define S_   1024
#define H_   768
#define NH_  12
#define DK_  64
#define M_   (B_ * S_)   // 8192

typedef __attribute__((ext_vector_type(8))) short          short8;
typedef __attribute__((ext_vector_type(8))) unsigned short ushort8;
typedef __attribute__((ext_vector_type(4))) float          f32x4;

__device__ __forceinline__ unsigned short f2bf(float x) {
    union { float f; unsigned u; } v; v.f = x;
    unsigned r = v.u + 0x7FFFu + ((v.u >> 16) & 1u);
    return (unsigned short)(r >> 16);
}

// ---------------------------------------------------------------------------
// y[M,N] = x[M,K] @ W[N,K]^T   (torch Linear, bias=False)
// 64x64 tile, BK=32, 4 waves (2x2 of 32x32), mfma_f32_16x16x32_bf16.
// ---------------------------------------------------------------------------
template<bool IN_BF16, bool OUT_BF16>
__global__ __launch_bounds__(256)
void gemm_xwT(const void* __restrict__ Xv, const float* __restrict__ W,
              void* __restrict__ Yv, int M, int N, int K)
{
    __shared__ unsigned short As[64][40];
    __shared__ unsigned short Bs[64][40];

    const int tid  = threadIdx.x;
    const int bm   = blockIdx.x, bn = blockIdx.y;
    const int sr   = tid >> 2;
    const int sc   = (tid & 3) * 8;
    const int wid  = tid >> 6;
    const int lane = tid & 63;
    const int wr   = wid >> 1, wc = wid & 1;
    const int lg   = lane >> 4, lc = lane & 15;

    const float*          Xf = (const float*)Xv;
    const unsigned short* Xh = (const unsigned short*)Xv;

    f32x4 acc[2][2] = {};

    for (int k0 = 0; k0 < K; k0 += 32) {
        {
            const size_t off = (size_t)(bm * 64 + sr) * K + k0 + sc;
            ushort8 a;
            if (IN_BF16) {
                a = *(const ushort8*)&Xh[off];
            } else {
                const float4 x0 = *(const float4*)&Xf[off];
                const float4 x1 = *(const float4*)&Xf[off + 4];
                a[0]=f2bf(x0.x); a[1]=f2bf(x0.y); a[2]=f2bf(x0.z); a[3]=f2bf(x0.w);
                a[4]=f2bf(x1.x); a[5]=f2bf(x1.y); a[6]=f2bf(x1.z); a[7]=f2bf(x1.w);
            }
            *(ushort8*)&As[sr][sc] = a;
        }
        {
            const size_t off = (size_t)(bn * 64 + sr) * K + k0 + sc;
            const float4 x0 = *(const float4*)&W[off];
            const float4 x1 = *(const float4*)&W[off + 4];
            ushort8 bvv;
            bvv[0]=f2bf(x0.x); bvv[1]=f2bf(x0.y); bvv[2]=f2bf(x0.z); bvv[3]=f2bf(x0.w);
            bvv[4]=f2bf(x1.x); bvv[5]=f2bf(x1.y); bvv[6]=f2bf(x1.z); bvv[7]=f2bf(x1.w);
            *(ushort8*)&Bs[sr][sc] = bvv;
        }
        __syncthreads();

        short8 af[2], bfr[2];
#pragma unroll
        for (int mi = 0; mi < 2; mi++)
            af[mi] = *(const short8*)&As[wr * 32 + mi * 16 + lc][lg * 8];
#pragma unroll
        for (int ni = 0; ni < 2; ni++)
            bfr[ni] = *(const short8*)&Bs[wc * 32 + ni * 16 + lc][lg * 8];
#pragma unroll
        for (int mi = 0; mi < 2; mi++)
#pragma unroll
            for (int ni = 0; ni < 2; ni++)
                acc[mi][ni] = __builtin_amdgcn_mfma_f32_16x16x32_bf16(
                    af[mi], bfr[ni], acc[mi][ni], 0, 0, 0);
        __syncthreads();
    }

#pragma unroll
    for (int mi = 0; mi < 2; mi++)
#pragma unroll
        for (int ni = 0; ni < 2; ni++)
#pragma unroll
            for (int reg = 0; reg < 4; reg++) {
                const int row = bm * 64 + wr * 32 + mi * 16 + lg * 4 + reg;
                const int col = bn * 64 + wc * 32 + ni * 16 + lc;
                const float val = acc[mi][ni][reg];
                if (OUT_BF16)
                    ((unsigned short*)Yv)[(size_t)row * N + col] = f2bf(val);
                else
                    ((float*)Yv)[(size_t)row * N + col] = val;
            }
}

// ---------------------------------------------------------------------------
// Flash attention: 1 block = (b, head, 64-row q tile). 4 waves x 16 q-rows.
// Conflict-free XOR-swizzled V-transpose + P buffer; Q fragments hoisted to
// registers (Q LDS region reused as P buffer). exp2-domain online softmax.
// ---------------------------------------------------------------------------
__global__ __launch_bounds__(256)
void attn(const unsigned short* __restrict__ q,
          const unsigned short* __restrict__ k,
          const unsigned short* __restrict__ v,
          unsigned short* __restrict__ c)
{
    __shared__ unsigned short Ks[64][72];
    __shared__ unsigned short Vt[64][72];   // Vt[d][key ^ ((d>>4)<<4)]
    __shared__ unsigned short Ps[64][72];   // staging for Q, then P tiles

    const int tid  = threadIdx.x;
    const int qt   = blockIdx.x, h = blockIdx.y, b = blockIdx.z;
    const int wid  = tid >> 6;
    const int lane = tid & 63;
    const int lg   = lane >> 4, lc = lane & 15;
    const int r    = tid >> 2;            // staging row (key or q row)
    const int d0   = (tid & 3) * 16;      // staging col base
    const int g    = tid & 3;             // d0 >> 4
    const size_t base = (size_t)b * S_ * H_ + (size_t)h * DK_;

    // stage Q tile into Ps (unswizzled), hoist fragments, then Ps is free for P
    {
        const unsigned short* src = &q[base + (size_t)(qt * 64 + r) * H_ + d0];
        *(ushort8*)&Ps[r][d0]     = *(const ushort8*)src;
        *(ushort8*)&Ps[r][d0 + 8] = *(const ushort8*)(src + 8);
    }
    __syncthreads();
    short8 aq[2];
#pragma unroll
    for (int ks = 0; ks < 2; ks++)
        aq[ks] = *(const short8*)&Ps[wid * 16 + lc][ks * 32 + lg * 8];

    f32x4 o[4] = {};
    float mrow[4], lrow[4];
#pragma unroll
    for (int i = 0; i < 4; i++) { mrow[i] = -1e30f; lrow[i] = 0.f; }

    const float SC = 0.125f * 1.44269504089f;   // log2(e)/sqrt(DK)

    for (int kt = 0; kt < S_ / 64; kt++) {
        // stage K tile (vectored) + V tile transposed with conflict-free swizzle
        {
            const unsigned short* ksrc = &k[base + (size_t)(kt * 64 + r) * H_ + d0];
            *(ushort8*)&Ks[r][d0]     = *(const ushort8*)ksrc;
            *(ushort8*)&Ks[r][d0 + 8] = *(const ushort8*)(ksrc + 8);
            const unsigned short* vsrc = &v[base + (size_t)(kt * 64 + r) * H_ + d0];
            const ushort8 v0 = *(const ushort8*)vsrc;
            const ushort8 v1 = *(const ushort8*)(vsrc + 8);
            const int colv = r ^ (g << 4);
#pragma unroll
            for (int j = 0; j < 8; j++) Vt[d0 + j][colv]     = v0[j];
#pragma unroll
            for (int j = 0; j < 8; j++) Vt[d0 + 8 + j][colv] = v1[j];
        }
        __syncthreads();

        // S = Q K^T  (wave's 16 q-rows x 64 keys)
        f32x4 s[4] = {};
#pragma unroll
        for (int ni = 0; ni < 4; ni++)
#pragma unroll
            for (int ks = 0; ks < 2; ks++) {
                const short8 bk = *(const short8*)&Ks[ni * 16 + lc][ks * 32 + lg * 8];
                s[ni] = __builtin_amdgcn_mfma_f32_16x16x32_bf16(aq[ks], bk, s[ni], 0, 0, 0);
            }

        // online softmax in exp2 domain (rows at lg*4+reg, key-cols at ni*16+lc)
#pragma unroll
        for (int reg = 0; reg < 4; reg++) {
            float pmax = -1e30f;
#pragma unroll
            for (int ni = 0; ni < 4; ni++) {
                s[ni][reg] *= SC;
                pmax = fmaxf(pmax, s[ni][reg]);
            }
#pragma unroll
            for (int d = 1; d < 16; d <<= 1)
                pmax = fmaxf(pmax, __shfl_xor(pmax, d, 64));
            const float mnew  = fmaxf(mrow[reg], pmax);
            const float scale = exp2f(mrow[reg] - mnew);
            float psum = 0.f;
#pragma unroll
            for (int ni = 0; ni < 4; ni++) {
                const float p = exp2f(s[ni][reg] - mnew);
                s[ni][reg] = p; psum += p;
            }
#pragma unroll
            for (int d = 1; d < 16; d <<= 1)
                psum += __shfl_xor(psum, d, 64);
            lrow[reg] = lrow[reg] * scale + psum;
            mrow[reg] = mnew;
            o[0][reg] *= scale; o[1][reg] *= scale;
            o[2][reg] *= scale; o[3][reg] *= scale;
        }

        // P -> LDS, swizzled: col' = col ^ (((row>>2)&3)<<4); wave-local region
#pragma unroll
        for (int ni = 0; ni < 4; ni++)
#pragma unroll
            for (int reg = 0; reg < 4; reg++)
                Ps[wid * 16 + lg * 4 + reg][(ni * 16 + lc) ^ (lg << 4)] =
                    f2bf(s[ni][reg]);

        short8 pa[2];
#pragma unroll
        for (int ks = 0; ks < 2; ks++)
            pa[ks] = *(const short8*)
                &Ps[wid * 16 + lc][(ks * 32 + lg * 8) ^ ((lc >> 2) << 4)];
#pragma unroll
        for (int ni = 0; ni < 4; ni++)
#pragma unroll
            for (int ks = 0; ks < 2; ks++) {
                const short8 bv = *(const short8*)
                    &Vt[ni * 16 + lc][(ks * 32 + lg * 8) ^ (ni << 4)];
                o[ni] = __builtin_amdgcn_mfma_f32_16x16x32_bf16(pa[ks], bv, o[ni], 0, 0, 0);
            }
        __syncthreads();
    }

    // write context (bf16) to c[B,S,H]
#pragma unroll
    for (int reg = 0; reg < 4; reg++) {
        const float inv = 1.0f / lrow[reg];
        const int row = qt * 64 + wid * 16 + lg * 4 + reg;
#pragma unroll
        for (int ni = 0; ni < 4; ni++)
            c[base + (size_t)row * H_ + ni * 16 + lc] = f2bf(o[ni][reg] * inv);
    }
}

// ---------------------------------------------------------------------------
extern "C" void kernel_launch(void* const* d_in, const int* in_sizes, int n_in,
                              void* d_out, int out_size, void* d_ws, size_t ws_size,
                              hipStream_t stream)
{
    const float* Q  = (const float*)d_in[0];
    const float* K  = (const float*)d_in[1];
    const float* V  = (const float*)d_in[2];
    const float* Wq = (const float*)d_in[3];
    const float* Wk = (const float*)d_in[4];
    const float* Wv = (const float*)d_in[5];
    const float* Wo = (const float*)d_in[6];

    unsigned short* qb = (unsigned short*)d_ws;
    unsigned short* kb = qb + (size_t)M_ * H_;
    unsigned short* vb = kb + (size_t)M_ * H_;
    unsigned short* cb = vb + (size_t)M_ * H_;

    const dim3 gg(M_ / 64, H_ / 64);   // 128 x 12

    gemm_xwT<false, true><<<gg, 256, 0, stream>>>(Q, Wq, qb, M_, H_, H_);
    gemm_xwT<false, true><<<gg, 256, 0, stream>>>(K, Wk, kb, M_, H_, H_);
    gemm_xwT<false, true><<<gg, 256, 0, stream>>>(V, Wv, vb, M_, H_, H_);

    attn<<<dim3(S_ / 64, NH_, B_), 256, 0, stream>>>(qb, kb, vb, cb);

    gemm_xwT<true, false><<<gg, 256, 0, stream>>>(cb, Wo, (float*)d_out, M_, H_, H_);
}